// Round 4
// baseline (92.691 us; speedup 1.0000x reference)
//
#include <hip/hip_runtime.h>
#include <math.h>

#define NE 8
#define ND 512
#define NB 16384
#define DV (ND / 4)            // float4s per (b, expert) row = 128
#define NBLK 2048              // grid-stride: 8 blocks/CU, 4 iterations each
#define TOTAL (NB * DV)        // 2,097,152 columns

typedef float f32x4 __attribute__((ext_vector_type(4)));

// Fused: entangled[b,i,:] = sum_j M[i][j]*x[b,j,:], M = I + sigmoid(corr)*(1-I)
// plus measure = |sum(entangled[0]^2)| / (E*D + 1e-8). b==0 (tids 0..127) is
// processed by block 0's first grid-stride iteration, so block 0 reduces its
// own accumulator registers — no output re-read, no extra launch.
__global__ __launch_bounds__(256) void fused_entangle(
        const f32x4* __restrict__ x,
        const float* __restrict__ corr,
        f32x4*       __restrict__ out,
        float*       __restrict__ measure_out) {
    __shared__ float sM[NE * NE];
    if (threadIdx.x < NE * NE) {
        int i = threadIdx.x >> 3, j = threadIdx.x & 7;
        float c = corr[threadIdx.x];
        float s = 1.0f / (1.0f + expf(-c));
        sM[threadIdx.x] = (i == j) ? 1.0f : s;
    }
    __syncthreads();

    float ssq = 0.f;
    for (int tid = blockIdx.x * 256 + threadIdx.x; tid < TOTAL; tid += NBLK * 256) {
        int b = tid >> 7;                               // / DV
        long base = (long)b * (NE * DV) + (tid & (DV - 1));

        f32x4 xv[NE];
#pragma unroll
        for (int j = 0; j < NE; ++j)
            xv[j] = __builtin_nontemporal_load(&x[base + j * DV]);

#pragma unroll
        for (int i = 0; i < NE; ++i) {
            f32x4 acc = (f32x4)(0.f);
#pragma unroll
            for (int j = 0; j < NE; ++j)
                acc = xv[j] * sM[i * NE + j] + acc;
            __builtin_nontemporal_store(acc, &out[base + i * DV]);
            if (b == 0)   // only tids 0..127 (block 0, first iteration)
                ssq += acc.x * acc.x + acc.y * acc.y + acc.z * acc.z + acc.w * acc.w;
        }
    }

    if (blockIdx.x == 0) {
        // deterministic block reduce: 64-lane shuffle, then LDS across 4 waves
#pragma unroll
        for (int off = 32; off > 0; off >>= 1)
            ssq += __shfl_down(ssq, off);
        __shared__ float ws[4];
        int lane = threadIdx.x & 63, w = threadIdx.x >> 6;
        if (lane == 0) ws[w] = ssq;
        __syncthreads();
        if (threadIdx.x == 0) {
            float t = ws[0] + ws[1] + ws[2] + ws[3];
            measure_out[0] = fabsf(t) / ((float)(NE * ND) + 1e-8f);
        }
    }
}

extern "C" void kernel_launch(void* const* d_in, const int* in_sizes, int n_in,
                              void* d_out, int out_size, void* d_ws, size_t ws_size,
                              hipStream_t stream) {
    const float* x    = (const float*)d_in[0];   // (16384, 8, 512) f32
    const float* corr = (const float*)d_in[1];   // (8, 8) f32
    float* out = (float*)d_out;                  // entangled flat + 1 measure

    fused_entangle<<<NBLK, 256, 0, stream>>>(
        (const f32x4*)x, corr, (f32x4*)out,
        out + (size_t)NB * NE * ND);
}